// Round 6
// baseline (244.596 us; speedup 1.0000x reference)
//
#include <hip/hip_runtime.h>

#define T_ 512
#define K_ 128
#define L2E 1.4426950408889634f
#define LN2 0.6931471805599453f

typedef _Float16 hv2 __attribute__((ext_vector_type(2)));

__device__ __forceinline__ int irl(int v, int lane) {
    return __builtin_amdgcn_readlane(v, lane);
}
__device__ __forceinline__ hv2 as_hv2(int i) { return __builtin_bit_cast(hv2, i); }
__device__ __forceinline__ hv2 pkh(float a, float b) {
    return __builtin_bit_cast(hv2, __builtin_amdgcn_cvt_pkrtz(a, b));
}
__device__ __forceinline__ int pk16(float a, float b) {
    return __builtin_bit_cast(int, __builtin_amdgcn_cvt_pkrtz(a, b));
}

#if __has_builtin(__builtin_amdgcn_fdot2)
#define FDOT2(a, b, c) __builtin_amdgcn_fdot2((a), (b), (c), false)
#else
__device__ __forceinline__ float fdot2_emu(hv2 a, hv2 b, float c) {
    return fmaf((float)a.x, (float)b.x, fmaf((float)a.y, (float)b.y, c));
}
#define FDOT2(a, b, c) fdot2_emu((a), (b), (c))
#endif

// wave64 max-reduce step via DPP (pure VALU, no lgkmcnt). values >= 0 so 0-fill safe.
#define DPPMAX(m, ctrl)                                                     \
    m = fmaxf(m, __int_as_float(__builtin_amdgcn_update_dpp(                 \
                     0, __float_as_int(m), (ctrl), 0xf, 0xf, true)))

// One step of the exponential-space recurrence. SLOT = h-prefetch register
// being refilled (read again 4 bodies later); SNEXT = h for step tt+1.
#define BODY(tt, SLOT, SNEXT)                                                \
    {                                                                        \
        const int tc = ((tt) + 4 < len) ? (tt) + 4 : len - 1;                \
        SLOT = hb[(size_t)tc * 64];                                          \
        float A0=0.f,A1=0.f,A2=0.f,A3=0.f,B0=0.f,B1=0.f,B2=0.f,B3=0.f;       \
        _Pragma("unroll")                                                    \
        for (int p = 0; p < 64; p += 4) {                                    \
            const hv2 x0 = as_hv2(irl(wpk, p));                              \
            const hv2 x1 = as_hv2(irl(wpk, p+1));                            \
            const hv2 x2 = as_hv2(irl(wpk, p+2));                            \
            const hv2 x3 = as_hv2(irl(wpk, p+3));                            \
            A0 = FDOT2(Ea[p],   x0, A0);                                     \
            B0 = FDOT2(Eb[p],   x0, B0);                                     \
            A1 = FDOT2(Ea[p+1], x1, A1);                                     \
            B1 = FDOT2(Eb[p+1], x1, B1);                                     \
            A2 = FDOT2(Ea[p+2], x2, A2);                                     \
            B2 = FDOT2(Eb[p+2], x2, B2);                                     \
            A3 = FDOT2(Ea[p+3], x3, A3);                                     \
            B3 = FDOT2(Eb[p+3], x3, B3);                                     \
        }                                                                    \
        w0 = ((A0+A1)+(A2+A3)) * ehc0;                                       \
        w1 = ((B0+B1)+(B2+B3)) * ehc1;                                       \
        wpk = pk16(w0, w1);                                                  \
        /* off-critical-path: build NEXT step's scale (lag-1, exact pow2) */ \
        CM2 += epend;                                                        \
        float m_ = fmaxf(w0, w1);                                            \
        DPPMAX(m_, 0x111); DPPMAX(m_, 0x112); DPPMAX(m_, 0x114);             \
        DPPMAX(m_, 0x118); DPPMAX(m_, 0x142); DPPMAX(m_, 0x143);             \
        const float mg = __int_as_float(irl(__float_as_int(m_), 63));        \
        const int   e_ = (int)(__float_as_uint(mg) >> 23) - 127;             \
        epend = (float)e_;                                                   \
        const float cn = __int_as_float((127 - e_) << 23);                   \
        ehc0 = exp2f(SNEXT.x * L2E) * cn;                                    \
        ehc1 = exp2f(SNEXT.y * L2E) * cn;                                    \
    }

// One wave per batch element. Lane l owns rows 2l, 2l+1.
// amdgpu_waves_per_eu(1,1): pin occupancy to 1 wave/EU so the compiler
// allocates E (128 dwords/lane) in ARCH VGPRs instead of AGPR-offloading
// (R5 showed VGPR_Count=88 < 128 -> accvgpr copy traffic on the matvec path).
__global__ __launch_bounds__(64)
__attribute__((amdgpu_waves_per_eu(1, 1)))
void crf_fwd(const float* __restrict__ h,
             const float* __restrict__ trans,
             const int* __restrict__ lengths,
             float* __restrict__ out)
{
    const int b  = blockIdx.x;
    const int l  = threadIdx.x;       // 0..63
    const int r0 = 2 * l, r1 = 2 * l + 1;

    // ---- one-time: E rows r0,r1 as packed f16 pairs over j ----
    hv2 Ea[64], Eb[64];
    {
        const float4* ta = reinterpret_cast<const float4*>(trans + r0 * K_);
        const float4* tb = reinterpret_cast<const float4*>(trans + r1 * K_);
#pragma unroll
        for (int q = 0; q < 32; ++q) {
            float4 x = ta[q];
            Ea[2*q]   = pkh(exp2f(x.x*L2E), exp2f(x.y*L2E));
            Ea[2*q+1] = pkh(exp2f(x.z*L2E), exp2f(x.w*L2E));
            float4 y = tb[q];
            Eb[2*q]   = pkh(exp2f(y.x*L2E), exp2f(y.y*L2E));
            Eb[2*q+1] = pkh(exp2f(y.z*L2E), exp2f(y.w*L2E));
        }
    }

    const int len = lengths[b];
    const float2* hb = reinterpret_cast<const float2*>(h + (size_t)b*(T_*K_) + r0);

    // state: w = scaled exp(score), one-hot at START=127 (lane 63 hi)
    float w0 = 0.0f, w1 = (l == 63) ? 1.0f : 0.0f;
    int   wpk = pk16(w0, w1);
    float CM2 = 0.0f;      // applied log2 scale total
    float epend = 0.0f;    // exponent of the scale baked into current ehc

    float2 s0 = hb[0];
    float2 s1 = hb[(size_t)((1 < len) ? 1 : len - 1) * 64];
    float2 s2 = hb[(size_t)((2 < len) ? 2 : len - 1) * 64];
    float2 s3 = hb[(size_t)((3 < len) ? 3 : len - 1) * 64];
    float ehc0 = exp2f(s0.x * L2E);   // c_0 = 1 (max of init w is 1)
    float ehc1 = exp2f(s0.y * L2E);

    int t = 0;
    const int nfull = len & ~3;
    for (; t < nfull; t += 4) {
        BODY(t+0, s0, s1);
        BODY(t+1, s1, s2);
        BODY(t+2, s2, s3);
        BODY(t+3, s3, s0);
    }
    if (t     < len) BODY(t,   s0, s1);
    if (t + 1 < len) BODY(t+1, s1, s2);
    if (t + 2 < len) BODY(t+2, s2, s3);

    // ---- out[b] = ln2 * (CM2 + log2( sum_i w[i] * exp(trans[END,i]) )) ----
    const float tEa = exp2f(trans[(K_-2)*K_ + r0] * L2E);
    const float tEb = exp2f(trans[(K_-2)*K_ + r1] * L2E);
    float s = w0 * tEa + w1 * tEb;
#pragma unroll
    for (int off = 32; off >= 1; off >>= 1)
        s += __shfl_xor(s, off, 64);
    if (l == 0) out[b] = (CM2 + log2f(s)) * LN2;
}

extern "C" void kernel_launch(void* const* d_in, const int* in_sizes, int n_in,
                              void* d_out, int out_size, void* d_ws, size_t ws_size,
                              hipStream_t stream) {
    const float* h       = (const float*)d_in[0];
    const float* trans   = (const float*)d_in[1];
    const int*   lengths = (const int*)d_in[2];
    float*       out     = (float*)d_out;
    const int B = in_sizes[2];   // 512
    crf_fwd<<<B, 64, 0, stream>>>(h, trans, lengths, out);
}